// Round 1
// baseline (275.968 us; speedup 1.0000x reference)
//
#include <hip/hip_runtime.h>
#include <math.h>

constexpr int L = 256;
constexpr float EPS = 1e-6f;

__device__ inline float wave_sum(float v) {
#pragma unroll
    for (int off = 32; off > 0; off >>= 1) v += __shfl_down(v, off, 64);
    return v;
}

// One block per sample. 256 threads.
__global__ __launch_bounds__(256) void per_sample_kernel(
    const float* __restrict__ Yp, const float* __restrict__ Yg,
    float* __restrict__ ratios) {
    const int b = blockIdx.x;
    const int t = threadIdx.x;
    const float* yp = Yp + (size_t)b * L * L;
    const float* yg = Yg + (size_t)b * L * L;
    const float4* yp4 = (const float4*)yp;
    const float4* yg4 = (const float4*)yg;

    __shared__ unsigned rowmask[8], colmask[8];
    __shared__ float part1[4], part2[4];
    __shared__ int s_anyg;
    __shared__ float s_sum_p, s_sum_pg;
    __shared__ int s_box[4];   // col_lo, col_hi, row_lo, row_hi
    __shared__ float s_par[4]; // gt0, gt1, inv_xr, inv_yr
    __shared__ int s_empty;

    if (t < 8) { rowmask[t] = 0u; colmask[t] = 0u; }
    if (t == 0) s_anyg = 0;
    __syncthreads();

    // Pass 1: full read of Yp and Yg (float4, coalesced).
    float sum_p = 0.f, sum_pg = 0.f;
    int anyg = 0;
#pragma unroll 4
    for (int k = 0; k < 64; ++k) {
        const int j = t + (k << 8);       // float4 index in [0, 16384)
        const float4 p = yp4[j];
        const float4 g = yg4[j];
        sum_p  += (p.x + p.y) + (p.z + p.w);
        sum_pg += p.x * g.x + p.y * g.y + p.z * g.z + p.w * g.w;
        anyg |= (g.x > 0.f) | (g.y > 0.f) | (g.z > 0.f) | (g.w > 0.f);
        const bool bx = p.x > 0.5f, by = p.y > 0.5f,
                   bz = p.z > 0.5f, bw = p.w > 0.5f;
        if (bx | by | bz | bw) {          // rare: only blob pixels exceed 0.5
            const int row = j >> 6;       // flat float idx = 4j; row = 4j>>8
            atomicOr(&rowmask[row >> 5], 1u << (row & 31));
            const int c0 = (j << 2) & 255;  // first col of this float4 (mult of 4)
            const unsigned bits =
                ((unsigned)bx | ((unsigned)by << 1) | ((unsigned)bz << 2) |
                 ((unsigned)bw << 3)) << (c0 & 31);
            atomicOr(&colmask[c0 >> 5], bits);
        }
    }
    if (anyg) atomicOr(&s_anyg, 1);

    float w1 = wave_sum(sum_p);
    float w2 = wave_sum(sum_pg);
    const int wave = t >> 6, lane = t & 63;
    if (lane == 0) { part1[wave] = w1; part2[wave] = w2; }
    __syncthreads();

    if (t == 0) {
        s_sum_p  = part1[0] + part1[1] + part1[2] + part1[3];
        s_sum_pg = part2[0] + part2[1] + part2[2] + part2[3];
        // Box bounds from 256-bit masks.
        int first_r = 0, last_r = 0, first_c = 0, last_c = 0;
        bool any_r = false, any_c = false;
        for (int i = 0; i < 8; ++i) {
            unsigned w = rowmask[i];
            if (w) {
                if (!any_r) { first_r = i * 32 + __builtin_ffs((int)w) - 1; any_r = true; }
                last_r = i * 32 + 31 - __builtin_clz(w);
            }
            unsigned wc = colmask[i];
            if (wc) {
                if (!any_c) { first_c = i * 32 + __builtin_ffs((int)wc) - 1; any_c = true; }
                last_c = i * 32 + 31 - __builtin_clz(wc);
            }
        }
        // Faithful to reference (incl. the row/col swap and floor division).
        const int left  = any_r ? first_r : 0;
        const int right = any_r ? (L - 1 - last_r) : 0;
        const int up    = any_c ? first_c : 0;
        const int down  = any_c ? (L - 1 - last_c) : 0;
        const int x_r = (right - left) >> 1;  // floor div (matches Python //)
        const int y_r = (down - up) >> 1;
        const float gt0 = (float)(left + x_r);  // compared against COLUMN coord
        const float gt1 = (float)(up + y_r);    // compared against ROW coord
        if (s_anyg || x_r == 0 || y_r == 0) {
            // gt branch taken, or mask provably all-zero (inf/nan -> h not > 0.1)
            s_empty = 1;
        } else {
            s_empty = 0;
            s_par[0] = gt0; s_par[1] = gt1;
            s_par[2] = 1.f / (float)x_r; s_par[3] = 1.f / (float)y_r;
            // mask needs d0^4+d1^4 < ln(10)*4/9 => |d0| <= 1.0059 ; pad a bit
            const float mx = fabsf((float)x_r) * 1.02f + 1.f;
            const float my = fabsf((float)y_r) * 1.02f + 1.f;
            s_box[0] = max(0, (int)floorf(gt0 - mx));
            s_box[1] = min(L - 1, (int)ceilf(gt0 + mx));
            s_box[2] = max(0, (int)floorf(gt1 - my));
            s_box[3] = min(L - 1, (int)ceilf(gt1 + my));
        }
    }
    __syncthreads();

    // Pass 2 (tiny): sum Yp over generated mask inside the bounding box.
    float pos_gen = 0.f;
    if (!s_empty) {
        const int cl = s_box[0], ch = s_box[1], rl = s_box[2], rh = s_box[3];
        const int W = ch - cl + 1, H = rh - rl + 1;
        const float gt0 = s_par[0], gt1 = s_par[1];
        const float inv_xr = s_par[2], inv_yr = s_par[3];
        for (int idx = t; idx < W * H; idx += 256) {
            const int r = rl + idx / W;
            const int c = cl + idx % W;
            float d0 = ((float)c - gt0) * inv_xr;
            float d1 = ((float)r - gt1) * inv_yr;
            d0 *= d0; d0 *= d0;   // d0^4
            d1 *= d1; d1 *= d1;   // d1^4
            const float h = __expf(-2.25f * (d0 + d1));  // exp(-h' / (2/3)^2)
            if (h > 0.1f) pos_gen += yp[r * L + c];
        }
    }
    float w3 = wave_sum(pos_gen);
    if (lane == 0) part1[wave] = w3;
    __syncthreads();
    if (t == 0) {
        const float positive =
            s_anyg ? s_sum_pg : (part1[0] + part1[1] + part1[2] + part1[3]);
        ratios[b] = (s_sum_p - positive) / (positive + EPS);
    }
}

__global__ __launch_bounds__(256) void finalize_kernel(
    const float* __restrict__ ratios, float* __restrict__ out, int B) {
    float v = 0.f;
    for (int i = threadIdx.x; i < B; i += 256) v += ratios[i];
    v = wave_sum(v);
    __shared__ float part[4];
    const int wave = threadIdx.x >> 6, lane = threadIdx.x & 63;
    if (lane == 0) part[wave] = v;
    __syncthreads();
    if (threadIdx.x == 0) {
        const float total = part[0] + part[1] + part[2] + part[3];
        out[0] = (total == 0.f) ? 0.f : logf(total) / (float)B;
    }
}

extern "C" void kernel_launch(void* const* d_in, const int* in_sizes, int n_in,
                              void* d_out, int out_size, void* d_ws, size_t ws_size,
                              hipStream_t stream) {
    const float* Yp = (const float*)d_in[0];
    const float* Yg = (const float*)d_in[1];
    const int B = in_sizes[0] / (L * L);
    float* ratios = (float*)d_ws;   // B floats of scratch
    per_sample_kernel<<<B, 256, 0, stream>>>(Yp, Yg, ratios);
    finalize_kernel<<<1, 256, 0, stream>>>(ratios, (float*)d_out, B);
}